// Round 8
// baseline (376.227 us; speedup 1.0000x reference)
//
#include <hip/hip_runtime.h>
#include <hip/hip_bf16.h>

// GCN pipeline on MI355X — MFMA bf16 GEMMs, fp32 accumulate, bf16 dataflow.
// R8: (a) gemm1 staging batches 8 float4 loads in flight (was 1 -> vmcnt(0)-serialized,
//         ~60 serial HBM latencies/wave = the 57us); cheap incremental row/col decode.
//     (b) agg_k: one wave per node, 4 edges in parallel (es=lane>>4), shfl_xor combine —
//         kills degree divergence + cuts dependent-gather chain 4x.

typedef __attribute__((ext_vector_type(8))) __bf16 bf16x8;
typedef __attribute__((ext_vector_type(4))) float f32x4;

// W [K][128] f32 -> Wt [128][Kp] bf16 (transpose + convert, zero-pad k>=K)
__global__ __launch_bounds__(256) void wtr_k(const float* __restrict__ W, ushort* __restrict__ Wt,
                                             int K, int Kp) {
  int idx = blockIdx.x * 256 + threadIdx.x;
  if (idx >= 128 * Kp) return;
  int n = idx / Kp, k = idx % Kp;
  float v = (k < K) ? W[(size_t)k * 128 + n] : 0.f;
  __hip_bfloat16 h = __float2bfloat16(v);
  Wt[idx] = *(ushort*)&h;
}

// ---------------- CSR build ----------------

__global__ __launch_bounds__(256) void zero_k(int* __restrict__ p, int n) {
  int i = blockIdx.x * 256 + threadIdx.x;
  if (i < n) p[i] = 0;
}

__global__ __launch_bounds__(256) void hist_k(const int* __restrict__ dst, int* __restrict__ cnt, int E) {
  int e = blockIdx.x * 256 + threadIdx.x;
  if (e < E) atomicAdd(&cnt[dst[e]], 1);
}

__global__ __launch_bounds__(256) void scan1_k(const int* __restrict__ cnt, int* __restrict__ rp,
                                               int* __restrict__ bsum, int N) {
  __shared__ int sd[256];
  int t = threadIdx.x;
  int base = blockIdx.x * 1024 + t * 4;
  int v0 = (base + 0 < N) ? cnt[base + 0] : 0;
  int v1 = (base + 1 < N) ? cnt[base + 1] : 0;
  int v2 = (base + 2 < N) ? cnt[base + 2] : 0;
  int v3 = (base + 3 < N) ? cnt[base + 3] : 0;
  int ts = v0 + v1 + v2 + v3;
  sd[t] = ts;
  __syncthreads();
  for (int off = 1; off < 256; off <<= 1) {
    int y = (t >= off) ? sd[t - off] : 0;
    __syncthreads();
    sd[t] += y;
    __syncthreads();
  }
  int x = sd[t] - ts;
  if (t == 255) bsum[blockIdx.x] = sd[255];
  if (base + 0 < N) rp[base + 0] = x; x += v0;
  if (base + 1 < N) rp[base + 1] = x; x += v1;
  if (base + 2 < N) rp[base + 2] = x; x += v2;
  if (base + 3 < N) rp[base + 3] = x;
}

__global__ __launch_bounds__(256) void scan2_k(int* __restrict__ bsum, int NB) {
  __shared__ int sd[256];
  int t = threadIdx.x;
  int base = t * 4;
  int v0 = (base + 0 < NB) ? bsum[base + 0] : 0;
  int v1 = (base + 1 < NB) ? bsum[base + 1] : 0;
  int v2 = (base + 2 < NB) ? bsum[base + 2] : 0;
  int v3 = (base + 3 < NB) ? bsum[base + 3] : 0;
  int ts = v0 + v1 + v2 + v3;
  sd[t] = ts;
  __syncthreads();
  for (int off = 1; off < 256; off <<= 1) {
    int y = (t >= off) ? sd[t - off] : 0;
    __syncthreads();
    sd[t] += y;
    __syncthreads();
  }
  int x = sd[t] - ts;
  if (base + 0 < NB) bsum[base + 0] = x; x += v0;
  if (base + 1 < NB) bsum[base + 1] = x; x += v1;
  if (base + 2 < NB) bsum[base + 2] = x; x += v2;
  if (base + 3 < NB) bsum[base + 3] = x;
}

__global__ __launch_bounds__(256) void scan3_k(int* __restrict__ rp, int* __restrict__ pos,
                                               const int* __restrict__ bsum,
                                               float* __restrict__ dinv, int N, int E) {
  int i = blockIdx.x * 256 + threadIdx.x;
  if (i < N) {
    int c = pos[i];  // pos aliases cnt: still the original count here
    int v = rp[i] + bsum[i >> 10];
    dinv[i] = rsqrtf((float)c + 1.0f);
    rp[i] = v;
    pos[i] = v;
  }
  if (i == 0) rp[N] = E;
}

__global__ __launch_bounds__(256) void fill_k(const int* __restrict__ src, const int* __restrict__ dst,
                                              const float* __restrict__ dinv,
                                              int* __restrict__ pos, int2* __restrict__ ew, int E) {
  int e = blockIdx.x * 256 + threadIdx.x;
  if (e < E) {
    int d = dst[e];
    int s = src[e];
    int idx = atomicAdd(&pos[d], 1);
    ew[idx] = make_int2(s, __float_as_int(dinv[s] * dinv[d]));
  }
}

// ---------------- GEMM1: hA = leaky(x[N,239] @ Wt^T + bias), bf16 out ----------------
// Flat-coalesced staging with 8 loads in flight; LDS Al 128x248 + Wl 128x72 = 80 KB.

__global__ __launch_bounds__(512, 4) void gemm1_k(const float* __restrict__ x,
                                                  const ushort* __restrict__ Wt,
                                                  const float* __restrict__ bias,
                                                  ushort* __restrict__ C, int N, int Ka,
                                                  unsigned long long M /* ceil(2^40/Ka) */) {
  __shared__ ushort Al[128 * 248];
  __shared__ ushort Wl[128 * 72];
  const int tid = threadIdx.x;
  const int wave = tid >> 6;
  const int lane = tid & 63;
  const int l16 = lane & 15;
  const int quad = lane >> 4;
  const int m0 = blockIdx.x * 128;

  // zero pad cols [239,248)
  if (tid < 128) {
    Al[tid * 248 + 239] = 0;
    *(uint4*)&Al[tid * 248 + 240] = make_uint4(0, 0, 0, 0);
  }

  // flat A staging: tile's x bytes are contiguous [m0*Ka, (m0+rows)*Ka)
  {
    int rows = N - m0;
    if (rows > 128) rows = 128;
    const int region = rows * Ka;
    const float* __restrict__ xb = x + (size_t)m0 * Ka;
    const int nv4 = region >> 2;
    const uint bump = 248u - (uint)Ka;  // LDS addr jump when crossing a row
    for (int i0 = tid; i0 < nv4; i0 += 512 * 8) {
      float4 v[8];
#pragma unroll
      for (int b = 0; b < 8; ++b) {
        int i = i0 + b * 512;
        if (i < nv4) v[b] = ((const float4*)xb)[i];  // 8 independent loads in flight
      }
#pragma unroll
      for (int b = 0; b < 8; ++b) {
        int i = i0 + b * 512;
        if (i < nv4) {
          uint idx = (uint)i * 4u;
          uint r = (uint)(((unsigned long long)idx * M) >> 40);
          uint c = idx - r * (uint)Ka;
          uint a0 = r * 248u + c;
          float vf[4] = {v[b].x, v[b].y, v[b].z, v[b].w};
#pragma unroll
          for (int j = 0; j < 4; ++j) {
            uint adr = a0 + j + ((c + j >= (uint)Ka) ? bump : 0u);
            __hip_bfloat16 h = __float2bfloat16(vf[j]);
            Al[adr] = *(ushort*)&h;
          }
        }
      }
    }
    for (int i = (nv4 << 2) + tid; i < region; i += 512) {  // scalar tail (normally empty)
      uint r = (uint)(((unsigned long long)(uint)i * M) >> 40);
      uint c = (uint)i - r * (uint)Ka;
      __hip_bfloat16 h = __float2bfloat16(xb[i]);
      Al[r * 248 + c] = *(ushort*)&h;
    }
  }

  f32x4 acc[8] = {};
  const int wn = tid >> 2;
  const int wseg = tid & 3;
#pragma unroll
  for (int kc = 0; kc < 4; ++kc) {
    __syncthreads();
    *(uint4*)&Wl[wn * 72 + wseg * 16] =
        *(const uint4*)(Wt + (size_t)wn * 256 + kc * 64 + wseg * 16);
    *(uint4*)&Wl[wn * 72 + wseg * 16 + 8] =
        *(const uint4*)(Wt + (size_t)wn * 256 + kc * 64 + wseg * 16 + 8);
    __syncthreads();
#pragma unroll
    for (int s = 0; s < 2; ++s) {
      const int koff = kc * 64 + s * 32 + quad * 8;
      bf16x8 a = {};
      if (koff < 248) a = *(const bf16x8*)&Al[(wave * 16 + l16) * 248 + koff];
      const int wof = s * 32 + quad * 8;
#pragma unroll
      for (int c = 0; c < 8; ++c) {
        bf16x8 b = *(const bf16x8*)&Wl[(c * 16 + l16) * 72 + wof];
        acc[c] = __builtin_amdgcn_mfma_f32_16x16x32_bf16(a, b, acc[c], 0, 0, 0);
      }
    }
  }

  float bv[8];
#pragma unroll
  for (int c = 0; c < 8; ++c) bv[c] = bias[c * 16 + l16];
#pragma unroll
  for (int reg = 0; reg < 4; ++reg) {
    int row = m0 + wave * 16 + quad * 4 + reg;
    if (row < N) {
#pragma unroll
      for (int c = 0; c < 8; ++c) {
        float v = acc[c][reg] + bv[c];
        v = v >= 0.f ? v : 0.01f * v;
        __hip_bfloat16 h = __float2bfloat16(v);
        C[(size_t)row * 128 + c * 16 + l16] = *(ushort*)&h;
      }
    }
  }
}

// ---------------- MFMA GEMM (bf16 A, K=128): C = A @ Wt^T ----------------
// MODE: 1 = bf16 + bias; 3 = fused leaky(.+bias)@W2 + b2 -> out[N,2] f32.

template <int MODE>
__global__ __launch_bounds__(512, 4) void mgemm_k(const ushort* __restrict__ A,
                                                  const ushort* __restrict__ Wt,
                                                  const float* __restrict__ bias,
                                                  const float* __restrict__ W2,
                                                  const float* __restrict__ b2,
                                                  void* __restrict__ C, int N) {
  __shared__ uint4 Al[128 * 16];
  __shared__ uint4 Wl[128 * 16];
  const int tid = threadIdx.x;
  const int wave = tid >> 6;
  const int lane = tid & 63;
  const int l16 = lane & 15;
  const int quad = lane >> 4;
  const int m0 = blockIdx.x * 128;

  f32x4 acc[8] = {};
  const int r_s = tid >> 4;
  const int j8 = tid & 15;
#pragma unroll
  for (int it = 0; it < 4; ++it) {
    int m = it * 32 + r_s;
    Al[m * 16 + (j8 ^ (m & 15))] = *(const uint4*)(A + (size_t)(m0 + m) * 128 + j8 * 8);
  }
#pragma unroll
  for (int it = 0; it < 4; ++it) {
    int n = it * 32 + r_s;
    Wl[n * 16 + (j8 ^ (n & 15))] = *(const uint4*)(Wt + (size_t)n * 128 + j8 * 8);
  }
  __syncthreads();
#pragma unroll
  for (int s = 0; s < 4; ++s) {
    const int j = s * 4 + quad;
    const int arow = wave * 16 + l16;
    bf16x8 a = *(const bf16x8*)&Al[arow * 16 + (j ^ (arow & 15))];
#pragma unroll
    for (int c = 0; c < 8; ++c) {
      const int brow = c * 16 + l16;
      bf16x8 b = *(const bf16x8*)&Wl[brow * 16 + (j ^ (brow & 15))];
      acc[c] = __builtin_amdgcn_mfma_f32_16x16x32_bf16(a, b, acc[c], 0, 0, 0);
    }
  }

  float bv[8];
#pragma unroll
  for (int c = 0; c < 8; ++c) bv[c] = bias[c * 16 + l16];

  if constexpr (MODE == 3) {
    float w20[8], w21[8];
#pragma unroll
    for (int c = 0; c < 8; ++c) {
      int colj = c * 16 + l16;
      w20[c] = W2[colj * 2 + 0];
      w21[c] = W2[colj * 2 + 1];
    }
    float bb0 = b2[0], bb1 = b2[1];
#pragma unroll
    for (int reg = 0; reg < 4; ++reg) {
      float o0 = 0.f, o1 = 0.f;
#pragma unroll
      for (int c = 0; c < 8; ++c) {
        float v = acc[c][reg] + bv[c];
        v = v >= 0.f ? v : 0.01f * v;
        o0 = fmaf(v, w20[c], o0);
        o1 = fmaf(v, w21[c], o1);
      }
      o0 += __shfl_xor(o0, 1); o0 += __shfl_xor(o0, 2);
      o0 += __shfl_xor(o0, 4); o0 += __shfl_xor(o0, 8);
      o1 += __shfl_xor(o1, 1); o1 += __shfl_xor(o1, 2);
      o1 += __shfl_xor(o1, 4); o1 += __shfl_xor(o1, 8);
      int row = m0 + wave * 16 + quad * 4 + reg;
      if (l16 == 0 && row < N)
        *(float2*)((float*)C + (size_t)row * 2) = make_float2(o0 + bb0, o1 + bb1);
    }
    return;
  }

#pragma unroll
  for (int reg = 0; reg < 4; ++reg) {
    int row = m0 + wave * 16 + quad * 4 + reg;
    if (row < N) {
#pragma unroll
      for (int c = 0; c < 8; ++c) {
        float v = acc[c][reg] + bv[c];
        __hip_bfloat16 h = __float2bfloat16(v);
        ((ushort*)C)[(size_t)row * 128 + c * 16 + l16] = *(ushort*)&h;
      }
    }
  }
}

// ---------------- CSR-pull aggregation, bf16 -> bf16 ----------------
// One WAVE per node: es = lane>>4 processes every 4th edge; l = lane&15 covers 16B of row.
// O[i] = sum_{e:dst=i} T[src]*w_e + T[i]*dinv[i]^2

__global__ __launch_bounds__(256) void agg_k(const ushort* __restrict__ T,
                                             const float* __restrict__ dinv,
                                             const int* __restrict__ rp,
                                             const int2* __restrict__ ew,
                                             ushort* __restrict__ O, int N) {
  const int node = blockIdx.x * 4 + (threadIdx.x >> 6);
  if (node >= N) return;
  const int lane = threadIdx.x & 63;
  const int es = lane >> 4;   // edge slot 0..3
  const int l = lane & 15;    // 16B chunk within row
  const uint4* T4 = (const uint4*)T;

  float a[8] = {0.f, 0.f, 0.f, 0.f, 0.f, 0.f, 0.f, 0.f};
  if (es == 0) {  // self-loop term
    float di = dinv[node];
    float dsq = di * di;
    uint4 sv = T4[(size_t)node * 16 + l];
    uint u[4] = {sv.x, sv.y, sv.z, sv.w};
#pragma unroll
    for (int p = 0; p < 4; ++p) {
      a[2 * p + 0] = __uint_as_float(u[p] << 16) * dsq;
      a[2 * p + 1] = __uint_as_float(u[p] & 0xFFFF0000u) * dsq;
    }
  }

  const int e0 = rp[node], e1 = rp[node + 1];
  for (int eb = e0; eb < e1; eb += 4) {
    int e = eb + es;
    bool act = e < e1;
    int2 pw = ew[act ? e : e0];
    float w = act ? __int_as_float(pw.y) : 0.f;
    uint4 v = T4[(size_t)pw.x * 16 + l];
    uint u[4] = {v.x, v.y, v.z, v.w};
#pragma unroll
    for (int p = 0; p < 4; ++p) {
      a[2 * p + 0] = fmaf(__uint_as_float(u[p] << 16), w, a[2 * p + 0]);
      a[2 * p + 1] = fmaf(__uint_as_float(u[p] & 0xFFFF0000u), w, a[2 * p + 1]);
    }
  }

  // combine the 4 edge slots (lanes l, l+16, l+32, l+48)
#pragma unroll
  for (int j = 0; j < 8; ++j) {
    a[j] += __shfl_xor(a[j], 16);
    a[j] += __shfl_xor(a[j], 32);
  }

  if (es == 0) {
    union { uint4 v; ushort s[8]; } uo;
#pragma unroll
    for (int j = 0; j < 8; ++j) {
      __hip_bfloat16 h = __float2bfloat16(a[j]);
      uo.s[j] = *(ushort*)&h;
    }
    ((uint4*)O)[(size_t)node * 16 + l] = uo.v;
  }
}

// ---------------- launch ----------------

extern "C" void kernel_launch(void* const* d_in, const int* in_sizes, int n_in,
                              void* d_out, int out_size, void* d_ws, size_t ws_size,
                              hipStream_t stream) {
  const float* x = (const float*)d_in[0];
  const int* ei = (const int*)d_in[1];
  const float* W_in = (const float*)d_in[3];
  const float* b_in = (const float*)d_in[4];
  const float* W_g  = (const float*)d_in[5];
  const float* b_g  = (const float*)d_in[6];
  const float* W_o1 = (const float*)d_in[7];
  const float* b_o1 = (const float*)d_in[8];
  const float* W_o2 = (const float*)d_in[9];
  const float* b_o2 = (const float*)d_in[10];

  const int D = in_sizes[4];        // 128
  const int ND = in_sizes[3] / D;   // 239
  const int N = in_sizes[0] / ND;   // 100000
  const int E = in_sizes[2];        // 640000
  const int* src = ei;
  const int* dst = ei + E;

  const int N_pad = ((N + 127) / 128) * 128;
  const size_t np = (size_t)N_pad;
  const int KP1 = 256;
  const unsigned long long MAGIC = ((1ULL << 40) + (unsigned)ND - 1) / (unsigned)ND;

  ushort* hA = (ushort*)d_ws;                 // np*128 bf16
  ushort* hB = hA + np * 128;                 // np*128 bf16
  ushort* Wt_in = hB + np * 128;              // 128*256 bf16
  ushort* Wt_g  = Wt_in + 128 * 256;          // 128*128
  ushort* Wt_o1 = Wt_g + 128 * 128;           // 128*128
  float* dinv = (float*)(Wt_o1 + 128 * 128);  // N f32
  int* cnt  = (int*)(dinv + N);
  int* rp   = cnt + N;
  int* bsum = rp + (N + 1);
  int2* ew  = (int2*)(((size_t)(bsum + 1024) + 7) & ~(size_t)7);

  const int NB = (N + 1023) / 1024;

  wtr_k<<<(128 * KP1 + 255) / 256, 256, 0, stream>>>(W_in, Wt_in, ND, KP1);
  wtr_k<<<(128 * 128 + 255) / 256, 256, 0, stream>>>(W_g, Wt_g, 128, 128);
  wtr_k<<<(128 * 128 + 255) / 256, 256, 0, stream>>>(W_o1, Wt_o1, 128, 128);

  zero_k<<<(N + 255) / 256, 256, 0, stream>>>(cnt, N);
  hist_k<<<(E + 255) / 256, 256, 0, stream>>>(dst, cnt, E);
  scan1_k<<<NB, 256, 0, stream>>>(cnt, rp, bsum, N);
  scan2_k<<<1, 256, 0, stream>>>(bsum, NB);
  scan3_k<<<(N + 255) / 256, 256, 0, stream>>>(rp, cnt /*pos*/, bsum, dinv, N, E);
  fill_k<<<(E + 255) / 256, 256, 0, stream>>>(src, dst, dinv, cnt, ew, E);

  const int gblocks = N_pad / 128;
  const int ablocks = (N + 3) / 4;
  gemm1_k<<<gblocks, 512, 0, stream>>>(x, Wt_in, b_in, hA, N, ND, MAGIC);
  agg_k<<<ablocks, 256, 0, stream>>>(hA, dinv, rp, ew, hB, N);
  mgemm_k<1><<<gblocks, 512, 0, stream>>>(hB, Wt_g, b_g, nullptr, nullptr, hA, N);
  agg_k<<<ablocks, 256, 0, stream>>>(hA, dinv, rp, ew, hB, N);
  mgemm_k<1><<<gblocks, 512, 0, stream>>>(hB, Wt_g, b_g, nullptr, nullptr, hA, N);
  mgemm_k<3><<<gblocks, 512, 0, stream>>>(hA, Wt_o1, b_o1, W_o2, b_o2, d_out, N);
}